// Round 1
// baseline (349.091 us; speedup 1.0000x reference)
//
#include <hip/hip_runtime.h>

#define NN 10000
#define NE 320000
#define FDIM 128
#define NRBF 20
#define PHI_DIM 384

// ---------------- node MLP: phi = silu(S@W1+b1)@W2 + b2 ----------------
__global__ void phi_kernel(const float* __restrict__ S, const float* __restrict__ W1,
                           const float* __restrict__ b1, const float* __restrict__ W2,
                           const float* __restrict__ b2, float* __restrict__ phi) {
  __shared__ float s_s[8][FDIM];
  __shared__ float h_s[8][FDIM];
  const int t = threadIdx.x;
  const int n0 = blockIdx.x * 8;
#pragma unroll
  for (int n = 0; n < 8; n++) s_s[n][t] = S[(n0 + n) * FDIM + t];
  __syncthreads();
  float acc[8];
#pragma unroll
  for (int n = 0; n < 8; n++) acc[n] = 0.f;
  for (int k = 0; k < FDIM; k++) {
    float w = W1[k * FDIM + t];
#pragma unroll
    for (int n = 0; n < 8; n++) acc[n] += s_s[n][k] * w;
  }
  float bb = b1[t];
#pragma unroll
  for (int n = 0; n < 8; n++) {
    float x = acc[n] + bb;
    h_s[n][t] = x / (1.0f + expf(-x));
  }
  __syncthreads();
  float a0[8], a1[8], a2[8];
#pragma unroll
  for (int n = 0; n < 8; n++) { a0[n] = 0.f; a1[n] = 0.f; a2[n] = 0.f; }
  for (int k = 0; k < FDIM; k++) {
    float w0 = W2[k * PHI_DIM + t];
    float w1 = W2[k * PHI_DIM + t + 128];
    float w2 = W2[k * PHI_DIM + t + 256];
#pragma unroll
    for (int n = 0; n < 8; n++) {
      float hv = h_s[n][k];
      a0[n] += hv * w0;
      a1[n] += hv * w1;
      a2[n] += hv * w2;
    }
  }
  float c0 = b2[t], c1 = b2[t + 128], c2 = b2[t + 256];
#pragma unroll
  for (int n = 0; n < 8; n++) {
    float* p = phi + (size_t)(n0 + n) * PHI_DIM;
    p[t] = a0[n] + c0;
    p[t + 128] = a1[n] + c1;
    p[t + 256] = a2[n] + c2;
  }
}

// ---------------- CSR build ----------------
__global__ void count_kernel(const int* __restrict__ idx_i, int* __restrict__ counts) {
  int e = blockIdx.x * blockDim.x + threadIdx.x;
  if (e < NE) atomicAdd(&counts[idx_i[e]], 1);
}

__global__ void scan_kernel(const int* __restrict__ counts, int* __restrict__ offsets) {
  __shared__ int s[1024];
  const int t = threadIdx.x;
  const int CH = 10;  // 1024*10 >= 10000
  int base = t * CH;
  int sum = 0;
#pragma unroll
  for (int i = 0; i < CH; i++) {
    int idx = base + i;
    if (idx < NN) sum += counts[idx];
  }
  s[t] = sum;
  __syncthreads();
  for (int off = 1; off < 1024; off <<= 1) {
    int v = (t >= off) ? s[t - off] : 0;
    __syncthreads();
    s[t] += v;
    __syncthreads();
  }
  int run = s[t] - sum;  // exclusive prefix
  for (int i = 0; i < CH; i++) {
    int idx = base + i;
    if (idx < NN) {
      offsets[idx] = run;
      run += counts[idx];
    }
  }
  if (t == 1023) offsets[NN] = s[1023];
}

__global__ void fill_kernel(const int* __restrict__ idx_i, const int* __restrict__ offsets,
                            int* __restrict__ cursor, int* __restrict__ elist) {
  int e = blockIdx.x * blockDim.x + threadIdx.x;
  if (e < NE) {
    int i = idx_i[e];
    int pos = atomicAdd(&cursor[i], 1);
    elist[offsets[i] + pos] = e;
  }
}

// ---------------- node-centric accumulation ----------------
__global__ void node_kernel(const int* __restrict__ idx_j, const float* __restrict__ rel_dir,
                            const float* __restrict__ cut, const float* __restrict__ rbf,
                            const float* __restrict__ Wr, const float* __restrict__ br,
                            const float* __restrict__ phi, const float* __restrict__ sf,
                            const float* __restrict__ vf, const int* __restrict__ offsets,
                            const int* __restrict__ elist, float* __restrict__ out) {
  __shared__ float wr_s[NRBF * PHI_DIM];  // 30720 B
  const int t = threadIdx.x;
  for (int i = t; i < NRBF * PHI_DIM; i += 128) wr_s[i] = Wr[i];
  __syncthreads();
  const int n = blockIdx.x;
  const int beg = offsets[n], end = offsets[n + 1];
  const float br0 = br[t], br1 = br[t + 128], br2 = br[t + 256];
  float ss_acc = 0.f;
  float vx = 0.f, vy = 0.f, vz = 0.f;
  for (int p = beg; p < end; p++) {
    int e = elist[p];
    int j = idx_j[e];
    float c = cut[e];
    float dx = rel_dir[e * 3 + 0], dy = rel_dir[e * 3 + 1], dz = rel_dir[e * 3 + 2];
    float rv[NRBF];
    const float4* rb4 = (const float4*)(rbf + (size_t)e * NRBF);  // 80B rows: 16B aligned
#pragma unroll
    for (int q = 0; q < 5; q++) {
      float4 v = rb4[q];
      rv[4 * q + 0] = v.x; rv[4 * q + 1] = v.y; rv[4 * q + 2] = v.z; rv[4 * q + 3] = v.w;
    }
    float g0 = br0, g1 = br1, g2 = br2;
#pragma unroll
    for (int r = 0; r < NRBF; r++) {
      float rvv = rv[r];
      g0 += rvv * wr_s[r * PHI_DIM + t];
      g1 += rvv * wr_s[r * PHI_DIM + t + 128];
      g2 += rvv * wr_s[r * PHI_DIM + t + 256];
    }
    g0 *= c; g1 *= c; g2 *= c;
    const float* pj = phi + (size_t)j * PHI_DIM;
    float vv = pj[t] * g0;
    float ss = pj[t + 128] * g1;
    float vs = pj[t + 256] * g2;
    ss_acc += ss;
    const float* vfj = vf + (size_t)j * (FDIM * 3) + t * 3;
    vx += vfj[0] * vv + vs * dx;
    vy += vfj[1] * vv + vs * dy;
    vz += vfj[2] * vv + vs * dz;
  }
  float cnt = (float)(end - beg);
  float inv = 1.0f / cnt;
  out[(size_t)n * FDIM + t] = sf[(size_t)n * FDIM + t] + ss_acc * inv;
  float* ov = out + (size_t)NN * FDIM + (size_t)n * (FDIM * 3) + t * 3;
  const float* iv = vf + (size_t)n * (FDIM * 3) + t * 3;
  ov[0] = iv[0] + vx * inv;
  ov[1] = iv[1] + vy * inv;
  ov[2] = iv[2] + vz * inv;
}

extern "C" void kernel_launch(void* const* d_in, const int* in_sizes, int n_in,
                              void* d_out, int out_size, void* d_ws, size_t ws_size,
                              hipStream_t stream) {
  const int* idx_i = (const int*)d_in[0];
  const int* idx_j = (const int*)d_in[1];
  const float* rel_dir = (const float*)d_in[2];
  const float* cut = (const float*)d_in[3];
  const float* rbf = (const float*)d_in[4];
  const float* sf = (const float*)d_in[5];
  const float* vf = (const float*)d_in[6];
  const float* W1 = (const float*)d_in[7];
  const float* b1 = (const float*)d_in[8];
  const float* W2 = (const float*)d_in[9];
  const float* b2 = (const float*)d_in[10];
  const float* Wr = (const float*)d_in[11];
  const float* br = (const float*)d_in[12];
  float* out = (float*)d_out;

  char* w = (char*)d_ws;
  int* counts = (int*)w;                          // 10000 ints
  int* cursor = (int*)(w + 40000);                // 10000 ints
  int* offsets = (int*)(w + 80000);               // 10001 ints (padded to 10016)
  int* elist = (int*)(w + 80000 + 40064);         // 320000 ints
  float* phi = (float*)(w + 80000 + 40064 + 1280000);  // 10000*384 floats

  hipMemsetAsync(w, 0, 80000, stream);  // zero counts + cursor
  hipLaunchKernelGGL(phi_kernel, dim3(NN / 8), dim3(128), 0, stream, sf, W1, b1, W2, b2, phi);
  hipLaunchKernelGGL(count_kernel, dim3((NE + 255) / 256), dim3(256), 0, stream, idx_i, counts);
  hipLaunchKernelGGL(scan_kernel, dim3(1), dim3(1024), 0, stream, counts, offsets);
  hipLaunchKernelGGL(fill_kernel, dim3((NE + 255) / 256), dim3(256), 0, stream, idx_i, offsets,
                     cursor, elist);
  hipLaunchKernelGGL(node_kernel, dim3(NN), dim3(128), 0, stream, idx_j, rel_dir, cut, rbf, Wr,
                     br, phi, sf, vf, offsets, elist, out);
}